// Round 4
// baseline (214.202 us; speedup 1.0000x reference)
//
#include <hip/hip_runtime.h>
#include <hip/hip_bf16.h>

// out[256, 100000] = (inputs[256,256] @ features[100000,256]^T) / 0.07
//
// v5 vs v4 (v4: 73.4 us, HBM 2.1 TB/s, MfmaUtil 6.6%, WRITE exact 100MB):
//  Elimination from rounds 0-3: not MFMA/VALU (<8%), not occupancy (GRID512
//  null), not barrier count (1 vs 2 null), not bank conflicts (0 vs 3.2M
//  null). Invariant: dur = 155MB / ~2.1 TB/s in every version. => The
//  kernel is BW-bound at a PATTERN-limited ~2.1 TB/s.
//  Fix: BN 64 -> 128.
//   - store locality: each block-iter now writes 512B (not 256B) per
//     output row -> half the DRAM row-activations GPU-wide.
//   - load duty cycle: 3.05 generations (was 6.1), 128KB load bursts.
//   - LDS = exactly 64KB: [128 rows][32 chunks] uint4v, single buffer,
//     v1-style 2-lgkm-barrier loop (proven equal to dbuf in v4).
//   - chunk-XOR swizzle (chunk ^= row&7): write side 8 lanes/bank-quad,
//     read side 2-way -> free per m136. Same family as v4, measured ok.
//   - regs: pf 32 + afrag 32 + acc 32 + addr ~20 ~= 115 < 128 -> 16 waves
//     at (1024,4) without spills (watch VGPR/WRITE for spill evidence).
//  Kept: operand-swapped MFMA (D holds 4 consecutive n per lane -> float4
//  stores), lgkm-only barriers (no vmcnt(0) drain), reg prefetch across
//  the barrier, scale folded into A.

typedef __attribute__((ext_vector_type(8))) __bf16 bf16x8;   // 4 VGPRs
typedef __attribute__((ext_vector_type(4))) float  floatx4;  // MFMA acc
typedef __attribute__((ext_vector_type(4))) unsigned int uint4v;

#define NB 100000
#define KD 256
#define BN 128
#define NTILES 782            // ceil(NB / BN)
#define GRID 256              // 1 persistent block per CU
#define NCHUNK 32             // 16B bf16 chunks per 128-col row

union FragCast { uint4v u; bf16x8 f; };

__device__ __forceinline__ unsigned pk(float a, float b) {
  // v_cvt_pk_bf16_f32 (RNE)
  __hip_bfloat162 h = __float22bfloat162_rn(float2{a, b});
  union { __hip_bfloat162 h2; unsigned u; } c; c.h2 = h; return c.u;
}

// Workgroup barrier with lgkmcnt(0) only -- no vmcnt(0) drain.
// All cross-wave hazards are LDS (lgkm); global stores have no reader and
// retire lazily; prefetch-load RAW is enforced by the compiler's counted
// vmcnt at the point the pf registers are consumed.
__device__ __forceinline__ void barrier_lgkm() {
  asm volatile("s_waitcnt lgkmcnt(0)" ::: "memory");
  __builtin_amdgcn_s_barrier();
  asm volatile("" ::: "memory");
}

__global__ __launch_bounds__(1024, 4)
void sct_gemm(const float* __restrict__ inputs,
              const float* __restrict__ features,
              float* __restrict__ out) {
  // bf16 B-tile, chunk-swizzled: 128 * 32 * 16B = 65536 B (full static LDS)
  __shared__ uint4v lds[BN][NCHUNK];

  const int tid  = threadIdx.x;
  const int ws   = tid >> 6;     // wave 0..15 -> m-subtile
  const int lane = tid & 63;
  const int quad = lane >> 4;
  const int l16  = lane & 15;
  const int q4   = quad * 4;
  const int e3   = l16 & 7;      // read-side swizzle key (= row&7 of read row)

  const int b = blockIdx.x;
  const int ntiles = (NTILES - b + GRID - 1) / GRID;

  // staging decomposition: thread covers 128B of one row:
  //   row = tid>>3 (0..127), k = tid&7 -> f32 bytes [k*128, k*128+128)
  const int srow = tid >> 3, sk = tid & 7;
  const int rswz = srow & 7;            // write-side swizzle key

  // ---- prefetch tile 0 into registers (8 float4 = 32 VGPRs) ----
  float4 pf[8];
  {
    const int n0 = b * BN;
    #pragma unroll
    for (int j = 0; j < 8; ++j) pf[j] = make_float4(0.f, 0.f, 0.f, 0.f);
    if (n0 + srow < NB) {
      const float4* p = (const float4*)(features + (size_t)(n0 + srow) * KD + sk * 32);
      #pragma unroll
      for (int j = 0; j < 8; ++j) pf[j] = p[j];
    }
  }

  // ---- A fragments (once per block), scale folded in ----
  const float scale = 1.0f / 0.07f;
  bf16x8 afrag[8];                         // 32 VGPRs
  {
    const float* arow = inputs + (ws * 16 + l16) * KD + quad * 8;
    #pragma unroll
    for (int t = 0; t < 8; ++t) {
      const float4* p = (const float4*)(arow + t * 32);
      const float4 a0 = p[0], a1 = p[1];
      FragCast fc;
      fc.u.x = pk(a0.x * scale, a0.y * scale);
      fc.u.y = pk(a0.z * scale, a0.w * scale);
      fc.u.z = pk(a1.x * scale, a1.y * scale);
      fc.u.w = pk(a1.z * scale, a1.w * scale);
      afrag[t] = fc.f;
    }
  }

  // lane's output row: m = ws*16 + l16 (operand-swapped D: 4 consecutive n
  // per lane at fixed m)
  float* const orow = out + (size_t)(ws * 16 + l16) * NB;

  for (int it = 0; it < ntiles; ++it) {
    const int n0 = (b + it * GRID) * BN;

    barrier_lgkm();   // all waves' LDS reads of previous tile retired

    // ---- stage current tile: convert prefetched f32 -> bf16 -> LDS ----
    // thread writes 4 swizzled 16B chunks of row srow: chunk (4k+j)^rswz
    {
      #pragma unroll
      for (int j = 0; j < 4; ++j) {
        uint4v w;
        w.x = pk(pf[2 * j].x, pf[2 * j].y);
        w.y = pk(pf[2 * j].z, pf[2 * j].w);
        w.z = pk(pf[2 * j + 1].x, pf[2 * j + 1].y);
        w.w = pk(pf[2 * j + 1].z, pf[2 * j + 1].w);
        lds[srow][(sk * 4 + j) ^ rswz] = w;
      }
    }

    barrier_lgkm();   // staged tile visible to all waves

    // ---- issue prefetch for next tile (consumed next iteration) ----
    if (it + 1 < ntiles) {
      const int nn0 = (b + (it + 1) * GRID) * BN;
      #pragma unroll
      for (int j = 0; j < 8; ++j) pf[j] = make_float4(0.f, 0.f, 0.f, 0.f);
      if (nn0 + srow < NB) {
        const float4* p = (const float4*)(features + (size_t)(nn0 + srow) * KD + sk * 32);
        #pragma unroll
        for (int j = 0; j < 8; ++j) pf[j] = p[j];
      }
    }

    // ---- MFMA (operand-swapped): 8 n-subtiles, K=256 in 8 steps ----
    floatx4 acc[8];
    #pragma unroll
    for (int nt = 0; nt < 8; ++nt) acc[nt] = floatx4{0.f, 0.f, 0.f, 0.f};

    #pragma unroll
    for (int t = 0; t < 8; ++t) {
      #pragma unroll
      for (int nt = 0; nt < 8; ++nt) {
        FragCast fc;
        // read row nt*16+l16 (row&7 == e3), chunk (t*4+quad)^e3
        fc.u = lds[nt * 16 + l16][(t * 4 + quad) ^ e3];
        acc[nt] = __builtin_amdgcn_mfma_f32_16x16x32_bf16(fc.f, afrag[t], acc[nt], 0, 0, 0);
      }
    }

    // ---- store: one float4 (4 consecutive n) per n-subtile ----
    #pragma unroll
    for (int nt = 0; nt < 8; ++nt) {
      const int n = n0 + nt * 16 + q4;
      if (n < NB)    // NB%4==0 so the float4 is all-in or all-out
        *(floatx4*)(orow + n) = acc[nt];
    }
  }
}

extern "C" void kernel_launch(void* const* d_in, const int* in_sizes, int n_in,
                              void* d_out, int out_size, void* d_ws, size_t ws_size,
                              hipStream_t stream) {
  const float* inputs   = (const float*)d_in[0];  // [256,256] f32
  // d_in[1] = indexes (unused), d_in[3] = momentum (unused)
  const float* features = (const float*)d_in[2];  // [100000,256] f32
  float* out = (float*)d_out;                     // [256,100000] f32

  sct_gemm<<<GRID, 1024, 0, stream>>>(inputs, features, out);
}

// Round 5
// 207.013 us; speedup vs baseline: 1.0347x; 1.0347x over previous
//
#include <hip/hip_runtime.h>
#include <hip/hip_bf16.h>

// out[256, 100000] = (inputs[256,256] @ features[100000,256]^T) / 0.07
//
// v6 vs v5 (v5 BN=128: 83.6us regression — spills at VGPR cap + conflicts;
//           reverted. Baseline remains v1/v4: 73.4us = 155MB @ 2.1 TB/s).
// Theory H3 (burst-and-stall): one 16-wave barrier-locked block per CU
// issues all its memory in a short burst between barriers, then the WHOLE
// CU goes memory-silent at the barrier -> average BW = burst BW x duty
// cycle ~ 2.1 TB/s. No intra-block restructure fixes this (v4 proved it:
// dbuf/1-barrier == 2-barrier). The lever is TWO independent scheduling
// entities per CU.
// v6: GRID=512 x 512 threads (8 waves). Block b: g=b&255 owns n-tile group
// g (n-tiles g, g+256, ...), mh=b>>8 owns M-rows [mh*128, mh*128+128).
// Blocks g and g+256 read the SAME features tile (same-CU under typical
// breadth-first dispatch -> L1/L2 shared; else L3 absorbs) but have
// INDEPENDENT barriers: one block's barrier stall overlaps the other's
// memory burst. Per-block: ~84 VGPR + 16 AGPR, 34.8KB LDS -> 2 blocks/CU
// fit (128-reg cap at (512,4), no v5-style spill).
// Kept (all proven): stride-136 LDS layout (0 bank conflicts, v3),
// 2-lgkm-barrier loop, loads-issued-before-stores (in-order vmcnt
// retirement => pf wait never waits store-acks), operand-swapped MFMA
// (4 consecutive n per lane -> float4 stores), scale folded into A.
// New micro: s_setprio(1) around MFMA — with 2 blocks at different phases
// per CU the scheduler now has something to arbitrate (T5 regime).

typedef __attribute__((ext_vector_type(8))) __bf16 bf16x8;   // 4 VGPRs
typedef __attribute__((ext_vector_type(4))) float  floatx4;  // MFMA acc
typedef __attribute__((ext_vector_type(4))) unsigned int uint4v;

#define NB 100000
#define KD 256
#define BN 64
#define NTILES 1563           // ceil(NB / BN)
#define GRID 512              // 256 n-groups x 2 m-halves
#define BLK 512               // 8 waves
#define LDS_STRIDE 136        // dwords/row: 128 data + 8 pad (0-conflict, v3)

union FragCast { uint4v u; bf16x8 f; };

__device__ __forceinline__ unsigned pk(float a, float b) {
  // v_cvt_pk_bf16_f32 (RNE)
  __hip_bfloat162 h = __float22bfloat162_rn(float2{a, b});
  union { __hip_bfloat162 h2; unsigned u; } c; c.h2 = h; return c.u;
}

// Workgroup barrier with lgkmcnt(0) only -- no vmcnt(0) drain.
// All cross-wave hazards are LDS (lgkm); global stores have no reader and
// retire lazily; prefetch-load RAW is enforced by the compiler's counted
// vmcnt at the point the pf registers are consumed (loads are older than
// stores in issue order, so their wait never waits on store-acks).
__device__ __forceinline__ void barrier_lgkm() {
  asm volatile("s_waitcnt lgkmcnt(0)" ::: "memory");
  __builtin_amdgcn_s_barrier();
  asm volatile("" ::: "memory");
}

__global__ __launch_bounds__(BLK, 4)
void sct_gemm(const float* __restrict__ inputs,
              const float* __restrict__ features,
              float* __restrict__ out) {
  __shared__ unsigned lds[BN * LDS_STRIDE];   // 34816 B bf16 B-tile

  const int tid  = threadIdx.x;
  const int ws   = tid >> 6;     // wave 0..7 -> m-subtile within half
  const int lane = tid & 63;
  const int quad = lane >> 4;
  const int l16  = lane & 15;
  const int q4   = quad * 4;

  const int g  = blockIdx.x & 255;   // n-tile group
  const int mh = blockIdx.x >> 8;    // m-half: rows [mh*128, mh*128+128)
  const int ntiles = (NTILES - g + 255) / 256;

  // staging: thread covers 32B chunk sck of rows srow+{0,16,32,48}
  const int srow = tid >> 5, sck = tid & 31;

  // ---- prefetch tile 0 into registers (4 rows x 2 float4 = 32 VGPRs) ----
  float4 pfa[4], pfb[4];
  {
    const int n0 = g * BN;
    #pragma unroll
    for (int j = 0; j < 4; ++j) {
      pfa[j] = pfb[j] = make_float4(0.f, 0.f, 0.f, 0.f);
      const int r = srow + j * 16;
      if (n0 + r < NB) {
        const float4* p = (const float4*)(features + (size_t)(n0 + r) * KD + sck * 8);
        pfa[j] = p[0]; pfb[j] = p[1];
      }
    }
  }

  // ---- A fragments (once per block), scale folded in ----
  const float scale = 1.0f / 0.07f;
  bf16x8 afrag[8];                         // 32 VGPRs
  {
    const float* arow = inputs + (mh * 128 + ws * 16 + l16) * KD + quad * 8;
    #pragma unroll
    for (int t = 0; t < 8; ++t) {
      const float4* p = (const float4*)(arow + t * 32);
      const float4 a0 = p[0], a1 = p[1];
      FragCast fc;
      fc.u.x = pk(a0.x * scale, a0.y * scale);
      fc.u.y = pk(a0.z * scale, a0.w * scale);
      fc.u.z = pk(a1.x * scale, a1.y * scale);
      fc.u.w = pk(a1.z * scale, a1.w * scale);
      afrag[t] = fc.f;
    }
  }

  // lane's output row: m = mh*128 + ws*16 + l16 (operand-swapped D:
  // 4 consecutive n per lane at fixed m)
  float* const orow = out + (size_t)(mh * 128 + ws * 16 + l16) * NB;

  for (int it = 0; it < ntiles; ++it) {
    const int n0 = (g + it * 256) * BN;

    barrier_lgkm();   // all waves' LDS reads of previous tile retired

    // ---- stage current tile: convert prefetched f32 -> bf16 -> LDS ----
    {
      #pragma unroll
      for (int j = 0; j < 4; ++j) {
        uint4v w;
        w.x = pk(pfa[j].x, pfa[j].y); w.y = pk(pfa[j].z, pfa[j].w);
        w.z = pk(pfb[j].x, pfb[j].y); w.w = pk(pfb[j].z, pfb[j].w);
        *(uint4v*)&lds[(srow + j * 16) * LDS_STRIDE + sck * 4] = w;
      }
    }

    barrier_lgkm();   // staged tile visible to all waves

    // ---- issue prefetch for next tile (consumed next iteration) ----
    if (it + 1 < ntiles) {
      const int nn0 = (g + (it + 1) * 256) * BN;
      #pragma unroll
      for (int j = 0; j < 4; ++j) {
        pfa[j] = pfb[j] = make_float4(0.f, 0.f, 0.f, 0.f);
        const int r = srow + j * 16;
        if (nn0 + r < NB) {
          const float4* p = (const float4*)(features + (size_t)(nn0 + r) * KD + sck * 8);
          pfa[j] = p[0]; pfb[j] = p[1];
        }
      }
    }

    // ---- MFMA (operand-swapped): 4 n-subtiles, K=256 in 8 steps ----
    floatx4 acc[4];
    #pragma unroll
    for (int nt = 0; nt < 4; ++nt) acc[nt] = floatx4{0.f, 0.f, 0.f, 0.f};

    __builtin_amdgcn_s_setprio(1);
    #pragma unroll
    for (int t = 0; t < 8; ++t) {
      #pragma unroll
      for (int nt = 0; nt < 4; ++nt) {
        FragCast fc;
        fc.u = *(const uint4v*)&lds[(nt * 16 + l16) * LDS_STRIDE + t * 16 + q4];
        acc[nt] = __builtin_amdgcn_mfma_f32_16x16x32_bf16(fc.f, afrag[t], acc[nt], 0, 0, 0);
      }
    }
    __builtin_amdgcn_s_setprio(0);

    // ---- store: one float4 (4 consecutive n) per n-subtile ----
    #pragma unroll
    for (int nt = 0; nt < 4; ++nt) {
      const int n = n0 + nt * 16 + q4;
      if (n < NB)    // NB%16==0 so the float4 is all-in or all-out
        *(floatx4*)(orow + n) = acc[nt];
    }
  }
}

extern "C" void kernel_launch(void* const* d_in, const int* in_sizes, int n_in,
                              void* d_out, int out_size, void* d_ws, size_t ws_size,
                              hipStream_t stream) {
  const float* inputs   = (const float*)d_in[0];  // [256,256] f32
  // d_in[1] = indexes (unused), d_in[3] = momentum (unused)
  const float* features = (const float*)d_in[2];  // [100000,256] f32
  float* out = (float*)d_out;                     // [256,100000] f32

  sct_gemm<<<GRID, BLK, 0, stream>>>(inputs, features, out);
}

// Round 6
// 199.061 us; speedup vs baseline: 1.0761x; 1.0399x over previous
//
#include <hip/hip_runtime.h>
#include <hip/hip_bf16.h>

// out[256, 100000] = (inputs[256,256] @ features[100000,256]^T) / 0.07
//
// v7 vs v6 (v6: 78us, HBM 2.6 TB/s but FETCH doubled by M-split dual-read).
// Theory (Little's law): per-CU achieved BW = bytes-in-flight / latency.
// v1/v4 hold only 32KB of loads in flight per CU (2 float4/thread, issued
// once per iteration then waited) -> 8 GB/s/CU -> 2.1 TB/s chip-wide,
// which matches EVERY measured variant that kept depth-1 prefetch. v6
// raised in-flight via a 2nd block and BW rose to 2.6 despite 2x fetch.
// Lever = prefetch DEPTH, which costs no duplicate fetch.
// v7 = v4 skeleton + depth-2 register prefetch:
//  - 1024 thr, GRID 256, full-M blocks: single-read of features restored
//    (FETCH should return to ~51MB).
//  - two STATIC prefetch sets A/B, loop unrolled x2 (rule #20: no runtime
//    indexing of reg arrays). Tile it is loaded 2 iterations early ->
//    ~64KB/CU loads perpetually in flight; staging's counted vmcnt wait
//    finds data already landed (newer set + stores stay outstanding).
//  - regs: pfA+pfB 32 + afrag 32 + acc 16 (AGPR) + temps ~20 ~= 100 < 128
//    cap at 16 waves (no v5-style spill).
// Kept (proven): stride-136 LDS (0 conflicts, v3/v6), lgkm-only barriers
// (no vmcnt(0) drain), operand-swapped MFMA (4 consecutive n per lane ->
// float4 stores, exact 100MB WRITE), scale folded into A. No setprio
// (null for lockstep blocks, m190).

typedef __attribute__((ext_vector_type(8))) __bf16 bf16x8;   // 4 VGPRs
typedef __attribute__((ext_vector_type(4))) float  floatx4;  // MFMA acc
typedef __attribute__((ext_vector_type(4))) unsigned int uint4v;

#define NB 100000
#define KD 256
#define BN 64
#define NTILES 1563           // ceil(NB / BN)
#define GRID 256              // 1 persistent block per CU
#define LDS_STRIDE 136        // dwords/row: 128 data + 8 pad (0-conflict)

union FragCast { uint4v u; bf16x8 f; };

__device__ __forceinline__ unsigned pk(float a, float b) {
  // v_cvt_pk_bf16_f32 (RNE)
  __hip_bfloat162 h = __float22bfloat162_rn(float2{a, b});
  union { __hip_bfloat162 h2; unsigned u; } c; c.h2 = h; return c.u;
}

// Workgroup barrier with lgkmcnt(0) only -- no vmcnt(0) drain.
// All cross-wave hazards are LDS (lgkm); global stores have no reader and
// retire lazily; prefetch-load RAW is enforced by the compiler's counted
// vmcnt at the point the pf registers are consumed.
__device__ __forceinline__ void barrier_lgkm() {
  asm volatile("s_waitcnt lgkmcnt(0)" ::: "memory");
  __builtin_amdgcn_s_barrier();
  asm volatile("" ::: "memory");
}

__global__ __launch_bounds__(1024, 4)
void sct_gemm(const float* __restrict__ inputs,
              const float* __restrict__ features,
              float* __restrict__ out) {
  __shared__ unsigned lds[BN * LDS_STRIDE];   // 34816 B bf16 B-tile

  const int tid  = threadIdx.x;
  const int ws   = tid >> 6;     // wave 0..15 -> m-subtile
  const int lane = tid & 63;
  const int quad = lane >> 4;
  const int l16  = lane & 15;
  const int q4   = quad * 4;

  const int b = blockIdx.x;
  const int ntiles = (NTILES - b + GRID - 1) / GRID;

  // staging: thread covers 32B chunk sck of rows srow and srow+32
  const int srow = tid >> 5, sck = tid & 31;

  // ---- depth-2 prefetch: set A = tile it (even), set B = tile it+1 ----
  float4 pfA0a, pfA0b, pfA1a, pfA1b;   // rows srow, srow+32 of even tile
  float4 pfB0a, pfB0b, pfB1a, pfB1b;   // rows srow, srow+32 of odd tile

#define ISSUE_PF(P0a, P0b, P1a, P1b, TN)                                      \
  {                                                                           \
    const int _n0 = (b + (TN) * GRID) * BN;                                   \
    P0a = P0b = P1a = P1b = make_float4(0.f, 0.f, 0.f, 0.f);                  \
    if (_n0 + srow < NB) {                                                    \
      const float4* _p = (const float4*)(features + (size_t)(_n0 + srow) * KD + sck * 8); \
      P0a = _p[0]; P0b = _p[1];                                               \
    }                                                                         \
    if (_n0 + srow + 32 < NB) {                                               \
      const float4* _p = (const float4*)(features + (size_t)(_n0 + srow + 32) * KD + sck * 8); \
      P1a = _p[0]; P1b = _p[1];                                               \
    }                                                                         \
  }

#define STAGE(P0a, P0b, P1a, P1b)                                             \
  {                                                                           \
    uint4v _w;                                                                \
    _w.x = pk(P0a.x, P0a.y); _w.y = pk(P0a.z, P0a.w);                         \
    _w.z = pk(P0b.x, P0b.y); _w.w = pk(P0b.z, P0b.w);                         \
    *(uint4v*)&lds[srow * LDS_STRIDE + sck * 4] = _w;                         \
    _w.x = pk(P1a.x, P1a.y); _w.y = pk(P1a.z, P1a.w);                         \
    _w.z = pk(P1b.x, P1b.y); _w.w = pk(P1b.z, P1b.w);                         \
    *(uint4v*)&lds[(srow + 32) * LDS_STRIDE + sck * 4] = _w;                  \
  }

#define COMPUTE_STORE(TN)                                                     \
  {                                                                           \
    const int _n0 = (b + (TN) * GRID) * BN;                                   \
    floatx4 acc[4];                                                           \
    _Pragma("unroll")                                                         \
    for (int nt = 0; nt < 4; ++nt) acc[nt] = floatx4{0.f, 0.f, 0.f, 0.f};     \
    _Pragma("unroll")                                                         \
    for (int t = 0; t < 8; ++t) {                                             \
      _Pragma("unroll")                                                       \
      for (int nt = 0; nt < 4; ++nt) {                                        \
        FragCast fc;                                                          \
        fc.u = *(const uint4v*)&lds[(nt * 16 + l16) * LDS_STRIDE + t * 16 + q4]; \
        acc[nt] = __builtin_amdgcn_mfma_f32_16x16x32_bf16(fc.f, afrag[t], acc[nt], 0, 0, 0); \
      }                                                                       \
    }                                                                         \
    _Pragma("unroll")                                                         \
    for (int nt = 0; nt < 4; ++nt) {                                          \
      const int _n = _n0 + nt * 16 + q4;                                      \
      if (_n < NB)                                                            \
        *(floatx4*)(orow + _n) = acc[nt];                                     \
    }                                                                         \
  }

  // ---- prologue: issue prefetch for tiles 0 and 1 ----
  ISSUE_PF(pfA0a, pfA0b, pfA1a, pfA1b, 0);
  if (1 < ntiles) { ISSUE_PF(pfB0a, pfB0b, pfB1a, pfB1b, 1); }

  // ---- A fragments (once per block), scale folded in ----
  const float scale = 1.0f / 0.07f;
  bf16x8 afrag[8];                         // 32 VGPRs
  {
    const float* arow = inputs + (ws * 16 + l16) * KD + quad * 8;
    #pragma unroll
    for (int t = 0; t < 8; ++t) {
      const float4* p = (const float4*)(arow + t * 32);
      const float4 a0 = p[0], a1 = p[1];
      FragCast fc;
      fc.u.x = pk(a0.x * scale, a0.y * scale);
      fc.u.y = pk(a0.z * scale, a0.w * scale);
      fc.u.z = pk(a1.x * scale, a1.y * scale);
      fc.u.w = pk(a1.z * scale, a1.w * scale);
      afrag[t] = fc.f;
    }
  }

  // lane's output row: m = ws*16 + l16 (operand-swapped D: 4 consecutive n
  // per lane at fixed m)
  float* const orow = out + (size_t)(ws * 16 + l16) * NB;

  for (int it = 0; it < ntiles; it += 2) {
    // ---- even iteration: tile it, set A ----
    barrier_lgkm();                    // prev tile's LDS reads retired
    STAGE(pfA0a, pfA0b, pfA1a, pfA1b); // counted vmcnt: only waits set A
    barrier_lgkm();                    // staged tile visible
    if (it + 2 < ntiles) { ISSUE_PF(pfA0a, pfA0b, pfA1a, pfA1b, it + 2); }
    COMPUTE_STORE(it);

    // ---- odd iteration: tile it+1, set B ----
    if (it + 1 < ntiles) {             // block-uniform branch
      barrier_lgkm();
      STAGE(pfB0a, pfB0b, pfB1a, pfB1b);
      barrier_lgkm();
      if (it + 3 < ntiles) { ISSUE_PF(pfB0a, pfB0b, pfB1a, pfB1b, it + 3); }
      COMPUTE_STORE(it + 1);
    }
  }
}

extern "C" void kernel_launch(void* const* d_in, const int* in_sizes, int n_in,
                              void* d_out, int out_size, void* d_ws, size_t ws_size,
                              hipStream_t stream) {
  const float* inputs   = (const float*)d_in[0];  // [256,256] f32
  // d_in[1] = indexes (unused), d_in[3] = momentum (unused)
  const float* features = (const float*)d_in[2];  // [100000,256] f32
  float* out = (float*)d_out;                     // [256,100000] f32

  sct_gemm<<<GRID, 1024, 0, stream>>>(inputs, features, out);
}